// Round 1
// baseline (151.279 us; speedup 1.0000x reference)
//
#include <hip/hip_runtime.h>
#include <math.h>

// Problem constants (from setup_inputs): feat (B=16, C=4, h=128, w=240),
// MAX_DISP=24, output (B,1,1024,1920) fp32.
#define BB 16
#define CC 4
#define HH 128
#define WW 240
#define MAXD 24
#define OH 1024
#define OW 1920

// Kernel A: cost volume + softmax-expectation + x8 scale -> pred (B,HH,WW) fp32 in ws.
// One block per (b,y) row; 256 threads, x = threadIdx.x (active x < 240).
__global__ __launch_bounds__(256) void pred_kernel(const float* __restrict__ fl,
                                                   const float* __restrict__ fr,
                                                   float* __restrict__ pred) {
    const int row = blockIdx.x;          // b*HH + y
    const int b = row / HH;
    const int y = row - b * HH;
    const int x = threadIdx.x;

    __shared__ float sL[CC][WW];
    __shared__ float sR[CC][WW + MAXD - 1];   // sR[c][23 + x] = feat_r[...,x]; first 23 = 0

    #pragma unroll
    for (int c = 0; c < CC; ++c) {
        const size_t idx = (((size_t)b * CC + c) * HH + y) * WW;
        if (x < WW) {
            sL[c][x] = fl[idx + x];
            sR[c][x + MAXD - 1] = fr[idx + x];
        }
        if (x < MAXD - 1) sR[c][x] = 0.0f;
    }
    __syncthreads();
    if (x >= WW) return;

    const float l0 = sL[0][x], l1 = sL[1][x], l2 = sL[2][x], l3 = sL[3][x];

    float cost[MAXD];
    float m = 1e30f;
    #pragma unroll
    for (int d = 0; d < MAXD; ++d) {
        const int xi = x - d + (MAXD - 1);   // >= 0 always
        const float cv = fabsf(l0 - sR[0][xi]) + fabsf(l1 - sR[1][xi])
                       + fabsf(l2 - sR[2][xi]) + fabsf(l3 - sR[3][xi]);
        cost[d] = cv;
        m = fminf(m, cv);
    }
    float s = 0.0f, wsum = 0.0f;
    #pragma unroll
    for (int d = 0; d < MAXD; ++d) {
        const float p = __expf(m - cost[d]);   // softmax(-cost), stabilized by min cost
        s += p;
        wsum += p * (float)d;
    }
    pred[(size_t)row * WW + x] = 8.0f * (wsum / s);   // * img_h / h = 1024/128
}

// Kernel B: bilinear align-corners resize (HH,WW) -> (OH,OW), float4 stores.
// One thread per 4 consecutive output x. Total threads = BB*OH*OW/4.
__global__ __launch_bounds__(256) void resize_kernel(const float* __restrict__ pred,
                                                     float* __restrict__ out) {
    const int tid = blockIdx.x * blockDim.x + threadIdx.x;
    const int QW = OW / 4;                 // 480
    const int xq = tid % QW;
    const int rest = tid / QW;
    const int oy = rest % OH;
    const int b = rest / OH;

    const float sy = (float)(HH - 1) / (float)(OH - 1);  // 127/1023
    const float sx = (float)(WW - 1) / (float)(OW - 1);  // 239/1919

    const float ysf = (float)oy * sy;
    int y0 = (int)ysf;
    if (y0 > HH - 1) y0 = HH - 1;
    const int y1 = min(y0 + 1, HH - 1);
    const float wy = ysf - (float)y0;

    const float* __restrict__ row0 = pred + ((size_t)b * HH + y0) * WW;
    const float* __restrict__ row1 = pred + ((size_t)b * HH + y1) * WW;

    float4 o;
    float* op = &o.x;
    #pragma unroll
    for (int i = 0; i < 4; ++i) {
        const int ox = xq * 4 + i;
        const float xsf = (float)ox * sx;
        int x0 = (int)xsf;
        if (x0 > WW - 1) x0 = WW - 1;
        const int x1 = min(x0 + 1, WW - 1);
        const float wx = xsf - (float)x0;
        const float r0 = row0[x0] + (row0[x1] - row0[x0]) * wx;
        const float r1 = row1[x0] + (row1[x1] - row1[x0]) * wx;
        op[i] = r0 + (r1 - r0) * wy;
    }
    ((float4*)out)[tid] = o;
}

extern "C" void kernel_launch(void* const* d_in, const int* in_sizes, int n_in,
                              void* d_out, int out_size, void* d_ws, size_t ws_size,
                              hipStream_t stream) {
    const float* feat_l = (const float*)d_in[0];
    const float* feat_r = (const float*)d_in[1];
    float* out = (float*)d_out;
    float* pred = (float*)d_ws;   // BB*HH*WW floats = 1.92 MB

    // Kernel A: one block per (b,y) row.
    pred_kernel<<<BB * HH, 256, 0, stream>>>(feat_l, feat_r, pred);

    // Kernel B: BB*OH*OW/4 threads.
    const int total_q = BB * OH * (OW / 4);           // 7,864,320
    resize_kernel<<<total_q / 256, 256, 0, stream>>>(pred, out);
}